// Round 7
// baseline (519.801 us; speedup 1.0000x reference)
//
#include <hip/hip_runtime.h>
#include <math.h>

// Problem constants
#define T_DIM 16
#define B_DIM 128
#define N_DIM 2048
#define TB    (T_DIM * B_DIM)   // 2048 rows of the GEMM

// Workspace layout (bytes). Total ~36.75 MB.
#define WS_H      0
#define WS_TSUM   33554432
#define WS_PSUM   35651584
#define WS_PSUM2  36175872
#define WS_SSUM   36700160
#define WS_SCALE  36716544
#define WS_SHIFT  36732928

typedef __attribute__((ext_vector_type(2))) double d2;

// ---- spatial sum over last dim: one block per (t,b) row -------------------
__global__ __launch_bounds__(256)
void spatial_sum_kernel(const float* __restrict__ x, double* __restrict__ ssum) {
    int row = blockIdx.x;           // 0..TB-1  (= t*B + b)
    int tid = threadIdx.x;
    const float* xr = x + (size_t)row * N_DIM;
    double s = 0.0;
    for (int i = tid; i < N_DIM; i += 256) s += (double)xr[i];
    for (int off = 32; off > 0; off >>= 1) s += __shfl_down(s, off, 64);
    __shared__ double wsum[4];
    int lane = tid & 63, wv = tid >> 6;
    if (lane == 0) wsum[wv] = s;
    __syncthreads();
    if (tid == 0) ssum[row] = (wsum[0] + wsum[1]) + (wsum[2] + wsum[3]);
}

// ---- temporal sum over t: one thread per (b,n) ----------------------------
__global__ __launch_bounds__(256)
void temporal_sum_kernel(const float* __restrict__ x, double* __restrict__ tsum) {
    int idx = blockIdx.x * 256 + threadIdx.x;     // b*N + n
    double s = 0.0;
    for (int t = 0; t < T_DIM; ++t)
        s += (double)x[(size_t)t * (B_DIM * N_DIM) + idx];
    tsum[idx] = s;
}

// ---- GEMM h[row,m] = sum_n x[row,n] * W[m,n], fp64 vector FMA -------------
// v6: 64x64 tile, TWO waves/block, in-block split-K, barrier-free PRIVATE
// staging as in v4 (f32, [k][row] stride 68: conflict-free both phases,
// 4x ds_read_b128 + 16 cvt + 64 v_fma_f64 per k-step) — v5's f64-A staging
// reverted (LDS pipe cost > cvt savings, measured 72% vs 81.7% busy).
// NEW: per-wave DOUBLE-BUFFERED staging: write prefetched tile into buf^1,
// issue next global load, compute from buf. Write->read distance = one full
// compute phase -> no lgkmcnt drain stall at tile boundaries.
// Epilogue: cross-wave combine + fused per-column BN partial stats.
// Per-element k-order unchanged -> h bit-identical (absmax 0.0).
#define BK 16
#define LDSS 68   // floats per k-row; 16B-aligned fragment reads
#define WBUF 4352 // bytes per single A-or-B buffer (1088 floats)
__global__ __launch_bounds__(128, 2)
void gemm_f64_v6(const float* __restrict__ A, const float* __restrict__ Bw,
                 double* __restrict__ C, double* __restrict__ psum,
                 double* __restrict__ psum2) {
    __shared__ __align__(16) char smem[34816];    // 2 waves x 2 bufs x 8704B; combine reuses 32KB
    const int t    = threadIdx.x;
    const int lane = t & 63;
    const int w    = t >> 6;                      // wave id 0/1
    const int tx   = lane & 7;                    // col 4-group
    const int ty   = lane >> 3;                   // row 4-group
    const int row0 = blockIdx.y * 64;
    const int col0 = blockIdx.x * 64;

    // wave-private double buffers: [buf][A|B]
    float* Abuf[2], * Bbuf[2];
    Abuf[0] = (float*)(smem + (size_t)w * 17408);
    Bbuf[0] = (float*)(smem + (size_t)w * 17408 + WBUF);
    Abuf[1] = (float*)(smem + (size_t)w * 17408 + 2 * WBUF);
    Bbuf[1] = (float*)(smem + (size_t)w * 17408 + 3 * WBUF);

    const float* Ag = A  + (size_t)(row0 + lane) * N_DIM;  // lane stages row `lane`
    const float* Bg = Bw + (size_t)(col0 + lane) * N_DIM;

    double acc[8][8];
#pragma unroll
    for (int i = 0; i < 8; ++i)
#pragma unroll
        for (int j = 0; j < 8; ++j) acc[i][j] = 0.0;

    const int kw = w * BK;                        // this wave's first k-tile
    float4 sa[4], sb[4];
#pragma unroll
    for (int j = 0; j < 4; ++j) {                 // load tile 0
        sa[j] = *(const float4*)(Ag + kw + 4 * j);
        sb[j] = *(const float4*)(Bg + kw + 4 * j);
    }
    {   // stage tile 0 into buf 0
        float* Ab = Abuf[0]; float* Bb = Bbuf[0];
#pragma unroll
        for (int j = 0; j < 4; ++j) {
            Ab[(4 * j + 0) * LDSS + lane] = sa[j].x;
            Ab[(4 * j + 1) * LDSS + lane] = sa[j].y;
            Ab[(4 * j + 2) * LDSS + lane] = sa[j].z;
            Ab[(4 * j + 3) * LDSS + lane] = sa[j].w;
            Bb[(4 * j + 0) * LDSS + lane] = sb[j].x;
            Bb[(4 * j + 1) * LDSS + lane] = sb[j].y;
            Bb[(4 * j + 2) * LDSS + lane] = sb[j].z;
            Bb[(4 * j + 3) * LDSS + lane] = sb[j].w;
        }
    }
    if (kw + 2 * BK < N_DIM) {                    // load tile 1
#pragma unroll
        for (int j = 0; j < 4; ++j) {
            sa[j] = *(const float4*)(Ag + kw + 2 * BK + 4 * j);
            sb[j] = *(const float4*)(Bg + kw + 2 * BK + 4 * j);
        }
    }

    int p = 0;
    for (int k0 = kw; k0 < N_DIM; k0 += 2 * BK) {
        const int knext = k0 + 2 * BK;
        if (knext < N_DIM) {
            // stage prefetched tile into the other buffer (no barrier needed)
            float* Ab = Abuf[p ^ 1]; float* Bb = Bbuf[p ^ 1];
#pragma unroll
            for (int j = 0; j < 4; ++j) {
                Ab[(4 * j + 0) * LDSS + lane] = sa[j].x;
                Ab[(4 * j + 1) * LDSS + lane] = sa[j].y;
                Ab[(4 * j + 2) * LDSS + lane] = sa[j].z;
                Ab[(4 * j + 3) * LDSS + lane] = sa[j].w;
                Bb[(4 * j + 0) * LDSS + lane] = sb[j].x;
                Bb[(4 * j + 1) * LDSS + lane] = sb[j].y;
                Bb[(4 * j + 2) * LDSS + lane] = sb[j].z;
                Bb[(4 * j + 3) * LDSS + lane] = sb[j].w;
            }
            if (knext + 2 * BK < N_DIM) {         // issue load of tile+2
#pragma unroll
                for (int j = 0; j < 4; ++j) {
                    sa[j] = *(const float4*)(Ag + knext + 2 * BK + 4 * j);
                    sb[j] = *(const float4*)(Bg + knext + 2 * BK + 4 * j);
                }
            }
        }
        // compute from buffer p
        const float* Ab = Abuf[p]; const float* Bb = Bbuf[p];
#pragma unroll
        for (int k = 0; k < BK; ++k) {
            float4 alo = *(const float4*)&Ab[k * LDSS + 4 * ty];
            float4 ahi = *(const float4*)&Ab[k * LDSS + 32 + 4 * ty];
            float4 blo = *(const float4*)&Bb[k * LDSS + 4 * tx];
            float4 bhi = *(const float4*)&Bb[k * LDSS + 32 + 4 * tx];
            double a[8], b[8];
            a[0] = (double)alo.x; a[1] = (double)alo.y;
            a[2] = (double)alo.z; a[3] = (double)alo.w;
            a[4] = (double)ahi.x; a[5] = (double)ahi.y;
            a[6] = (double)ahi.z; a[7] = (double)ahi.w;
            b[0] = (double)blo.x; b[1] = (double)blo.y;
            b[2] = (double)blo.z; b[3] = (double)blo.w;
            b[4] = (double)bhi.x; b[5] = (double)bhi.y;
            b[6] = (double)bhi.z; b[7] = (double)bhi.w;
#pragma unroll
            for (int i = 0; i < 8; ++i)
#pragma unroll
                for (int j = 0; j < 8; ++j)
                    acc[i][j] = fma(a[i], b[j], acc[i][j]);
        }
        p ^= 1;
    }

    // ---- cross-wave combine: wave1 -> LDS, wave0 adds into acc ----
    __syncthreads();
    double* cbuf = (double*)smem;    // 4096 doubles = 32KB
    if (w == 1) {
#pragma unroll
        for (int e = 0; e < 64; ++e)
            cbuf[e * 64 + lane] = acc[e >> 3][e & 7];
    }
    __syncthreads();
    if (w == 0) {
#pragma unroll
        for (int i = 0; i < 8; ++i)
#pragma unroll
            for (int j = 0; j < 8; ++j)
                acc[i][j] += cbuf[(i * 8 + j) * 64 + lane];

        // store C
#pragma unroll
        for (int i = 0; i < 8; ++i) {
            int r = row0 + ((i < 4) ? (4 * ty + i) : (32 + 4 * ty + i - 4));
            double* Crow = C + (size_t)r * N_DIM + col0;
#pragma unroll
            for (int jg = 0; jg < 2; ++jg) {
                int cbase = (jg == 0) ? (4 * tx) : (32 + 4 * tx);
                d2 v0, v1;
                v0.x = acc[i][4 * jg + 0]; v0.y = acc[i][4 * jg + 1];
                v1.x = acc[i][4 * jg + 2]; v1.y = acc[i][4 * jg + 3];
                *(d2*)(Crow + cbase)     = v0;
                *(d2*)(Crow + cbase + 2) = v1;
            }
        }

        // per-column partial BN stats over this block's 64 rows (deterministic)
        double s[8], q[8];
#pragma unroll
        for (int j = 0; j < 8; ++j) { s[j] = 0.0; q[j] = 0.0; }
#pragma unroll
        for (int i = 0; i < 8; ++i)
#pragma unroll
            for (int j = 0; j < 8; ++j) {
                double v = acc[i][j];
                s[j] += v;
                q[j] = fma(v, v, q[j]);
            }
#pragma unroll
        for (int off = 8; off <= 32; off <<= 1)
#pragma unroll
            for (int j = 0; j < 8; ++j) {
                s[j] += __shfl_xor(s[j], off, 64);
                q[j] += __shfl_xor(q[j], off, 64);
            }
        if (ty == 0) {               // lanes 0..7 hold column totals
            int band = blockIdx.y;
#pragma unroll
            for (int jg = 0; jg < 2; ++jg)
#pragma unroll
                for (int jj = 0; jj < 4; ++jj) {
                    int c = col0 + ((jg == 0) ? (4 * tx + jj) : (32 + 4 * tx + jj));
                    psum [band * N_DIM + c] = s[4 * jg + jj];
                    psum2[band * N_DIM + c] = q[4 * jg + jj];
                }
        }
    }
}

// ---- BN final: reduce 32 rowband partials, build scale/shift --------------
__global__ __launch_bounds__(256)
void col_stats_final(const double* __restrict__ psum, const double* __restrict__ psum2,
                     const float* __restrict__ gamma, const float* __restrict__ beta,
                     double* __restrict__ scale, double* __restrict__ shift) {
    int m = blockIdx.x * 256 + threadIdx.x;
    double s = 0.0, s2 = 0.0;
    for (int c = 0; c < 32; ++c) { s += psum[c * N_DIM + m]; s2 += psum2[c * N_DIM + m]; }
    double mean = s * (1.0 / 2048.0);
    double var = s2 * (1.0 / 2048.0) - mean * mean;
    double istd = 1.0 / sqrt(var + 1e-5);
    double sc = istd * (double)gamma[m];
    scale[m] = sc;
    shift[m] = (double)beta[m] - mean * sc;
}

// ---- fused BN-apply + triple LIF + output ---------------------------------
__global__ __launch_bounds__(256)
void fused_lif_kernel(const float* __restrict__ x, const double* __restrict__ h,
                      const double* __restrict__ scale, const double* __restrict__ shift,
                      const double* __restrict__ ssum, const double* __restrict__ tsum,
                      float* __restrict__ out) {
    int idx = blockIdx.x * 256 + threadIdx.x;     // b*N + n
    int n = idx & (N_DIM - 1);
    int b = idx >> 11;
    double sc = scale[n], sh = shift[n];
    double ts = tsum[idx];
    double v1 = 0.0, v2 = 0.0, v3 = 0.0;
    for (int t = 0; t < T_DIM; ++t) {
        size_t off = (size_t)(t * B_DIM + b) * N_DIM + n;
        double hv = fma(h[off], sc, sh);
        v1 = v1 * 0.5 + hv;
        bool s1 = (v1 >= 1.0); if (s1) v1 = 0.0;
        double in2 = s1 ? ssum[t * B_DIM + b] : 0.0;
        v2 = v2 * 0.5 + in2;
        bool s2 = (v2 >= 1.0); if (s2) v2 = 0.0;
        double in3 = s1 ? ts : 0.0;
        v3 = v3 * 0.5 + in3;
        bool s3 = (v3 >= 1.0); if (s3) v3 = 0.0;
        out[off] = x[off] + ((s2 && s3) ? 1.0f : 0.0f);
    }
}

extern "C" void kernel_launch(void* const* d_in, const int* in_sizes, int n_in,
                              void* d_out, int out_size, void* d_ws, size_t ws_size,
                              hipStream_t stream) {
    const float* x     = (const float*)d_in[0];   // [16,128,2048]
    const float* W     = (const float*)d_in[1];   // [2048,2048]
    const float* gamma = (const float*)d_in[2];   // [2048]
    const float* beta  = (const float*)d_in[3];   // [2048]
    float* out = (float*)d_out;

    char* ws = (char*)d_ws;
    double* h     = (double*)(ws + WS_H);
    double* tsum  = (double*)(ws + WS_TSUM);
    double* psum  = (double*)(ws + WS_PSUM);
    double* psum2 = (double*)(ws + WS_PSUM2);
    double* ssum  = (double*)(ws + WS_SSUM);
    double* scale = (double*)(ws + WS_SCALE);
    double* shift = (double*)(ws + WS_SHIFT);

    spatial_sum_kernel<<<TB, 256, 0, stream>>>(x, ssum);
    temporal_sum_kernel<<<(B_DIM * N_DIM) / 256, 256, 0, stream>>>(x, tsum);
    gemm_f64_v6<<<dim3(N_DIM / 64, TB / 64), 128, 0, stream>>>(x, W, h, psum, psum2);
    col_stats_final<<<8, 256, 0, stream>>>(psum, psum2, gamma, beta, scale, shift);
    fused_lif_kernel<<<(B_DIM * N_DIM) / 256, 256, 0, stream>>>(x, h, scale, shift, ssum, tsum, out);
}

// Round 8
// 446.736 us; speedup vs baseline: 1.1636x; 1.1636x over previous
//
#include <hip/hip_runtime.h>
#include <math.h>

// Problem constants
#define T_DIM 16
#define B_DIM 128
#define N_DIM 2048
#define TB    (T_DIM * B_DIM)   // 2048 rows of the GEMM

// Workspace layout (bytes). Total ~36.75 MB.
#define WS_H      0
#define WS_TSUM   33554432
#define WS_PSUM   35651584
#define WS_PSUM2  36175872
#define WS_SSUM   36700160
#define WS_SCALE  36716544
#define WS_SHIFT  36732928

typedef __attribute__((ext_vector_type(2))) double d2;
typedef __attribute__((ext_vector_type(4))) float f4;

// async global->LDS DMA, 16B per lane: LDS dest = wave-uniform base + lane*16
#define GLD_LDS16(gp, lp)                                                     \
    __builtin_amdgcn_global_load_lds(                                         \
        (const __attribute__((address_space(1))) unsigned int*)(const void*)(gp), \
        (__attribute__((address_space(3))) unsigned int*)(void*)(lp), 16, 0, 0)

// ---- spatial sum over last dim: one block per (t,b) row -------------------
__global__ __launch_bounds__(256)
void spatial_sum_kernel(const float* __restrict__ x, double* __restrict__ ssum) {
    int row = blockIdx.x;           // 0..TB-1  (= t*B + b)
    int tid = threadIdx.x;
    const float* xr = x + (size_t)row * N_DIM;
    double s = 0.0;
    for (int i = tid; i < N_DIM; i += 256) s += (double)xr[i];
    for (int off = 32; off > 0; off >>= 1) s += __shfl_down(s, off, 64);
    __shared__ double wsum[4];
    int lane = tid & 63, wv = tid >> 6;
    if (lane == 0) wsum[wv] = s;
    __syncthreads();
    if (tid == 0) ssum[row] = (wsum[0] + wsum[1]) + (wsum[2] + wsum[3]);
}

// ---- temporal sum over t: one thread per (b,n) ----------------------------
__global__ __launch_bounds__(256)
void temporal_sum_kernel(const float* __restrict__ x, double* __restrict__ tsum) {
    int idx = blockIdx.x * 256 + threadIdx.x;     // b*N + n
    double s = 0.0;
    for (int t = 0; t < T_DIM; ++t)
        s += (double)x[(size_t)t * (B_DIM * N_DIM) + idx];
    tsum[idx] = s;
}

// ---- GEMM h[row,m] = sum_n x[row,n] * W[m,n], fp64 vector FMA -------------
// v7: 64x64 tile, TWO waves/block, in-block split-K (wave w: k-tiles
// w*16 + 32i). Staging via global_load_lds dwordx4 DMA into wave-private
// DOUBLE-buffered LDS (no VGPR round-trip, no ds_writes), paced with
// explicit s_waitcnt vmcnt(8): issue 8 loads for tile t+1, wait for tile
// t's 8, compute. DMA forces LDS pos = lane*16, so lane l fetches global
// row g(l) = (l&32)|((l&7)<<2)|((l>>3)&3); then row 4ty+i sits at pos
// ty+8i and all fragment b128 reads hit 8 distinct bank quads
// (conflict-free, 8-lane broadcast). k ascending per output element and
// wave0+wave1 combine unchanged -> h bit-identical (absmax 0.0).
#define BK 16
__global__ __launch_bounds__(128, 2)
void gemm_f64_v7(const float* __restrict__ A, const float* __restrict__ Bw,
                 double* __restrict__ C, double* __restrict__ psum,
                 double* __restrict__ psum2) {
    __shared__ __align__(16) char smem[32768];    // 2 waves x 2 bufs x 8KB; combine reuses 32KB
    const int t    = threadIdx.x;
    const int lane = t & 63;
    const int w    = t >> 6;                      // wave id 0/1
    const int tx   = lane & 7;                    // col 4-group
    const int ty   = (lane >> 3) & 7;             // row 4-group
    const int row0 = blockIdx.y * 64;
    const int col0 = blockIdx.x * 64;
    const int g    = (lane & 32) | ((lane & 7) << 2) | ((lane >> 3) & 3);

    float* base = (float*)(smem + (size_t)w * 16384);   // wave-private
    // buffer p: A at base + p*2048, B at base + p*2048 + 1024 (floats)

    const float* Ag = A  + (size_t)(row0 + g) * N_DIM;  // lane fetches row g(lane)
    const float* Bg = Bw + (size_t)(col0 + g) * N_DIM;

    double acc[8][8];
#pragma unroll
    for (int i = 0; i < 8; ++i)
#pragma unroll
        for (int j = 0; j < 8; ++j) acc[i][j] = 0.0;

    const int kw = w * BK;                        // this wave's first k-tile
    // issue tile 0 DMA into buf 0
#pragma unroll
    for (int j = 0; j < 4; ++j) {
        GLD_LDS16(Ag + kw + 4 * j, base + j * 256);
        GLD_LDS16(Bg + kw + 4 * j, base + 1024 + j * 256);
    }

    int p = 0;
    for (int k0 = kw; k0 < N_DIM; k0 += 2 * BK) {
        const int knext = k0 + 2 * BK;
        if (knext < N_DIM) {
            float* nb = base + (p ^ 1) * 2048;    // issue tile t+1 DMA
#pragma unroll
            for (int j = 0; j < 4; ++j) {
                GLD_LDS16(Ag + knext + 4 * j, nb + j * 256);
                GLD_LDS16(Bg + knext + 4 * j, nb + 1024 + j * 256);
            }
            asm volatile("s_waitcnt vmcnt(8)" ::: "memory");  // tile t landed
        } else {
            asm volatile("s_waitcnt vmcnt(0)" ::: "memory");
        }
        const float* Ab = base + p * 2048;
        const float* Bb = Ab + 1024;
#pragma unroll
        for (int jc = 0; jc < 4; ++jc) {          // 4 k-chunks of 4
            f4 af[8], bf[8];
#pragma unroll
            for (int i = 0; i < 4; ++i) {
                af[i]     = *(const f4*)&Ab[jc * 256 + (ty + 8 * i) * 4];
                af[4 + i] = *(const f4*)&Ab[jc * 256 + (32 + ty + 8 * i) * 4];
                bf[i]     = *(const f4*)&Bb[jc * 256 + (tx + 8 * i) * 4];
                bf[4 + i] = *(const f4*)&Bb[jc * 256 + (32 + tx + 8 * i) * 4];
            }
            // af[i][e] = A[row 4ty+i][k0+4jc+e]; af[4+i] = row 32+4ty+i
#pragma unroll
            for (int e = 0; e < 4; ++e) {         // k-steps, ascending
                double a[8], b[8];
#pragma unroll
                for (int r = 0; r < 4; ++r) {
                    a[r]     = (double)af[r][e];
                    a[4 + r] = (double)af[4 + r][e];
                    b[r]     = (double)bf[r][e];
                    b[4 + r] = (double)bf[4 + r][e];
                }
                // remap reg index -> logical row/col: rows {4ty+r, 32+4ty+r}
                // a[r]: r<4 low rows r, r>=4 high rows; same for b. acc[i][j]
                // uses i: 0..3 rows 4ty+i, 4..7 rows 32+4ty+(i-4) — matches.
#pragma unroll
                for (int i = 0; i < 8; ++i)
#pragma unroll
                    for (int j = 0; j < 8; ++j)
                        acc[i][j] = fma(a[i], b[j], acc[i][j]);
            }
        }
        p ^= 1;
    }

    // ---- cross-wave combine: wave1 -> LDS, wave0 adds into acc ----
    __syncthreads();
    double* cbuf = (double*)smem;    // 4096 doubles = 32KB
    if (w == 1) {
#pragma unroll
        for (int e = 0; e < 64; ++e)
            cbuf[e * 64 + lane] = acc[e >> 3][e & 7];
    }
    __syncthreads();
    if (w == 0) {
#pragma unroll
        for (int i = 0; i < 8; ++i)
#pragma unroll
            for (int j = 0; j < 8; ++j)
                acc[i][j] += cbuf[(i * 8 + j) * 64 + lane];

        // store C: rows {4ty+i, 32+4ty+i}, cols {4tx+j, 32+4tx+j}
#pragma unroll
        for (int i = 0; i < 8; ++i) {
            int r = row0 + ((i < 4) ? (4 * ty + i) : (32 + 4 * ty + i - 4));
            double* Crow = C + (size_t)r * N_DIM + col0;
#pragma unroll
            for (int jg = 0; jg < 2; ++jg) {
                int cbase = (jg == 0) ? (4 * tx) : (32 + 4 * tx);
                d2 v0, v1;
                v0.x = acc[i][4 * jg + 0]; v0.y = acc[i][4 * jg + 1];
                v1.x = acc[i][4 * jg + 2]; v1.y = acc[i][4 * jg + 3];
                *(d2*)(Crow + cbase)     = v0;
                *(d2*)(Crow + cbase + 2) = v1;
            }
        }

        // per-column partial BN stats over this block's 64 rows (deterministic)
        double s[8], q[8];
#pragma unroll
        for (int j = 0; j < 8; ++j) { s[j] = 0.0; q[j] = 0.0; }
#pragma unroll
        for (int i = 0; i < 8; ++i)
#pragma unroll
            for (int j = 0; j < 8; ++j) {
                double v = acc[i][j];
                s[j] += v;
                q[j] = fma(v, v, q[j]);
            }
#pragma unroll
        for (int off = 8; off <= 32; off <<= 1)
#pragma unroll
            for (int j = 0; j < 8; ++j) {
                s[j] += __shfl_xor(s[j], off, 64);
                q[j] += __shfl_xor(q[j], off, 64);
            }
        if (ty == 0) {               // lanes 0..7 hold column totals
            int band = blockIdx.y;
#pragma unroll
            for (int jg = 0; jg < 2; ++jg)
#pragma unroll
                for (int jj = 0; jj < 4; ++jj) {
                    int c = col0 + ((jg == 0) ? (4 * tx + jj) : (32 + 4 * tx + jj));
                    psum [band * N_DIM + c] = s[4 * jg + jj];
                    psum2[band * N_DIM + c] = q[4 * jg + jj];
                }
        }
    }
}

// ---- BN final: reduce 32 rowband partials, build scale/shift --------------
__global__ __launch_bounds__(256)
void col_stats_final(const double* __restrict__ psum, const double* __restrict__ psum2,
                     const float* __restrict__ gamma, const float* __restrict__ beta,
                     double* __restrict__ scale, double* __restrict__ shift) {
    int m = blockIdx.x * 256 + threadIdx.x;
    double s = 0.0, s2 = 0.0;
    for (int c = 0; c < 32; ++c) { s += psum[c * N_DIM + m]; s2 += psum2[c * N_DIM + m]; }
    double mean = s * (1.0 / 2048.0);
    double var = s2 * (1.0 / 2048.0) - mean * mean;
    double istd = 1.0 / sqrt(var + 1e-5);
    double sc = istd * (double)gamma[m];
    scale[m] = sc;
    shift[m] = (double)beta[m] - mean * sc;
}

// ---- fused BN-apply + triple LIF + output ---------------------------------
__global__ __launch_bounds__(256)
void fused_lif_kernel(const float* __restrict__ x, const double* __restrict__ h,
                      const double* __restrict__ scale, const double* __restrict__ shift,
                      const double* __restrict__ ssum, const double* __restrict__ tsum,
                      float* __restrict__ out) {
    int idx = blockIdx.x * 256 + threadIdx.x;     // b*N + n
    int n = idx & (N_DIM - 1);
    int b = idx >> 11;
    double sc = scale[n], sh = shift[n];
    double ts = tsum[idx];
    double v1 = 0.0, v2 = 0.0, v3 = 0.0;
    for (int t = 0; t < T_DIM; ++t) {
        size_t off = (size_t)(t * B_DIM + b) * N_DIM + n;
        double hv = fma(h[off], sc, sh);
        v1 = v1 * 0.5 + hv;
        bool s1 = (v1 >= 1.0); if (s1) v1 = 0.0;
        double in2 = s1 ? ssum[t * B_DIM + b] : 0.0;
        v2 = v2 * 0.5 + in2;
        bool s2 = (v2 >= 1.0); if (s2) v2 = 0.0;
        double in3 = s1 ? ts : 0.0;
        v3 = v3 * 0.5 + in3;
        bool s3 = (v3 >= 1.0); if (s3) v3 = 0.0;
        out[off] = x[off] + ((s2 && s3) ? 1.0f : 0.0f);
    }
}

extern "C" void kernel_launch(void* const* d_in, const int* in_sizes, int n_in,
                              void* d_out, int out_size, void* d_ws, size_t ws_size,
                              hipStream_t stream) {
    const float* x     = (const float*)d_in[0];   // [16,128,2048]
    const float* W     = (const float*)d_in[1];   // [2048,2048]
    const float* gamma = (const float*)d_in[2];   // [2048]
    const float* beta  = (const float*)d_in[3];   // [2048]
    float* out = (float*)d_out;

    char* ws = (char*)d_ws;
    double* h     = (double*)(ws + WS_H);
    double* tsum  = (double*)(ws + WS_TSUM);
    double* psum  = (double*)(ws + WS_PSUM);
    double* psum2 = (double*)(ws + WS_PSUM2);
    double* ssum  = (double*)(ws + WS_SSUM);
    double* scale = (double*)(ws + WS_SCALE);
    double* shift = (double*)(ws + WS_SHIFT);

    spatial_sum_kernel<<<TB, 256, 0, stream>>>(x, ssum);
    temporal_sum_kernel<<<(B_DIM * N_DIM) / 256, 256, 0, stream>>>(x, tsum);
    gemm_f64_v7<<<dim3(N_DIM / 64, TB / 64), 128, 0, stream>>>(x, W, h, psum, psum2);
    col_stats_final<<<8, 256, 0, stream>>>(psum, psum2, gamma, beta, scale, shift);
    fused_lif_kernel<<<(B_DIM * N_DIM) / 256, 256, 0, stream>>>(x, h, scale, shift, ssum, tsum, out);
}

// Round 10
// 372.890 us; speedup vs baseline: 1.3940x; 1.1980x over previous
//
#include <hip/hip_runtime.h>
#include <math.h>

// Problem constants
#define T_DIM 16
#define B_DIM 128
#define N_DIM 2048
#define TB    (T_DIM * B_DIM)   // 2048 rows of the GEMM

// Workspace layout (bytes). Total ~36.2 MB.
#define WS_H      0
#define WS_TSUM   33554432
#define WS_PSUM   35651584
#define WS_PSUM2  35913728
#define WS_SSUM   36175872
#define WS_SCALE  36192256
#define WS_SHIFT  36208640
#define WS_FLAG   36225024

typedef __attribute__((ext_vector_type(2))) double d2;
typedef __attribute__((ext_vector_type(4))) double d4;

// ---- MFMA f64 wiring probe -------------------------------------------------
// Integer-valued test matrices: all products/sums exact in fp64, so the true
// hypothesis scores err == 0 and any wrong wiring scores >= 1.
__device__ __forceinline__ double probeA(int m, int k) {
    return (double)((m * 7 + k * 13) % 23 - 11);
}
__device__ __forceinline__ double probeB(int k, int n) {
    return (double)((k * 5 + n * 3) % 19 - 9);
}

// Hypothesis encoding fh = ab*4 + dF;  ab = aF + 2*bF.
//  A-form 0: m=l&15,k=l>>4   1: m=l>>2,k=l&3
//  B-form 0: n=l&15,k=l>>4   1: n=l>>2,k=l&3
//  D-form 0: i=4*(l>>4)+r,j=l&15   1: i=(l>>4)+4r,j=l&15
//         2: j=4*(l>>4)+r,i=l&15   3: j=(l>>4)+4r,i=l&15
__global__ void mfma_probe_kernel(unsigned int* flag) {
    int l = threadIdx.x;                 // one wave
    __shared__ double Cref[16][16];
    int i0 = l >> 2, j0 = (l & 3) << 2;  // each lane computes 4 ref elements
    for (int jj = 0; jj < 4; ++jj) {
        double s = 0.0;
        for (int k = 0; k < 4; ++k) s += probeA(i0, k) * probeB(k, j0 + jj);
        Cref[i0][j0 + jj] = s;
    }
    __syncthreads();
    unsigned int win = 0xFFFFFFFFu;
    for (int ab = 0; ab < 4; ++ab) {
        int aF = ab & 1, bF = (ab >> 1) & 1;
        int mA = aF ? (l >> 2) : (l & 15);
        int kA = aF ? (l & 3)  : (l >> 4);
        int nB = bF ? (l >> 2) : (l & 15);
        int kB = bF ? (l & 3)  : (l >> 4);
        d4 d = (d4)0.0;
        d = __builtin_amdgcn_mfma_f64_16x16x4f64(probeA(mA, kA), probeB(kB, nB), d, 0, 0, 0);
        for (int dF = 0; dF < 4; ++dF) {
            double err = 0.0;
            for (int r = 0; r < 4; ++r) {
                int ii, jj;
                if (dF == 0)      { ii = 4 * (l >> 4) + r; jj = l & 15; }
                else if (dF == 1) { ii = (l >> 4) + 4 * r; jj = l & 15; }
                else if (dF == 2) { jj = 4 * (l >> 4) + r; ii = l & 15; }
                else              { jj = (l >> 4) + 4 * r; ii = l & 15; }
                err = fmax(err, fabs(d[r] - Cref[ii][jj]));
            }
            for (int off = 1; off < 64; off <<= 1)
                err = fmax(err, __shfl_xor(err, off, 64));
            if (err < 1e-9 && win == 0xFFFFFFFFu)
                win = (unsigned)(ab * 4 + dF);
        }
    }
    if (l == 0) flag[0] = win;
}

// ---- spatial sum over last dim: one block per (t,b) row -------------------
__global__ __launch_bounds__(256)
void spatial_sum_kernel(const float* __restrict__ x, double* __restrict__ ssum) {
    int row = blockIdx.x;           // 0..TB-1  (= t*B + b)
    int tid = threadIdx.x;
    const float* xr = x + (size_t)row * N_DIM;
    double s = 0.0;
    for (int i = tid; i < N_DIM; i += 256) s += (double)xr[i];
    for (int off = 32; off > 0; off >>= 1) s += __shfl_down(s, off, 64);
    __shared__ double wsum[4];
    int lane = tid & 63, wv = tid >> 6;
    if (lane == 0) wsum[wv] = s;
    __syncthreads();
    if (tid == 0) ssum[row] = (wsum[0] + wsum[1]) + (wsum[2] + wsum[3]);
}

// ---- temporal sum over t: one thread per (b,n) ----------------------------
__global__ __launch_bounds__(256)
void temporal_sum_kernel(const float* __restrict__ x, double* __restrict__ tsum) {
    int idx = blockIdx.x * 256 + threadIdx.x;     // b*N + n
    double s = 0.0;
    for (int t = 0; t < T_DIM; ++t)
        s += (double)x[(size_t)t * (B_DIM * N_DIM) + idx];
    tsum[idx] = s;
}

// ---- GEMM h[row,m] = sum_n x[row,n] * W[m,n] ------------------------------
// v9 hybrid: 64x64 tile, TWO waves/block, in-block split-K, barrier-free
// per-wave PRIVATE f32 staging (v4 structure, proven 391 us / absmax 0.0).
// If the probe found the f64-MFMA wiring (flag<=15), compute on the matrix
// pipe with runtime-parameterized fragment reads and C-store indices;
// otherwise fall back to the v4 vector-FMA path. Either path: fp64
// accumulation of exact fp64(f32) products -> spike margins (~1e-6) dwarf
// fp64 noise (~1e-13).
#define BK 16
#define LDSS 68   // vector path: f32 stride per k-row
#define STRD 80   // mfma path:   f32 stride per k-row (2-way aliasing = free)
__global__ __launch_bounds__(128, 2)
void gemm_hybrid(const float* __restrict__ A, const float* __restrict__ Bw,
                 double* __restrict__ C, const unsigned int* __restrict__ flag) {
    __shared__ __align__(16) char smem[32768];
    const int t    = threadIdx.x;
    const int lane = t & 63;
    const int w    = t >> 6;                      // wave id 0/1
    const int row0 = blockIdx.y * 64;
    const int col0 = blockIdx.x * 64;
    const unsigned int fh = flag[0];

    const float* Ag = A  + (size_t)(row0 + lane) * N_DIM;  // lane stages row `lane`
    const float* Bg = Bw + (size_t)(col0 + lane) * N_DIM;
    const int kw = w * BK;                        // this wave's first k-tile

    if (fh <= 15u) {
        // ================= MFMA path =================
        const int dF = fh & 3, ab = fh >> 2;
        const int aF = ab & 1, bF = (ab >> 1) & 1;
        const int mA = aF ? (lane >> 2) : (lane & 15);
        const int kA = aF ? (lane & 3)  : (lane >> 4);
        const int nB = bF ? (lane >> 2) : (lane & 15);
        const int kB = bF ? (lane & 3)  : (lane >> 4);
        int iD[4], jD[4];
#pragma unroll
        for (int r = 0; r < 4; ++r) {
            if (dF == 0)      { iD[r] = 4 * (lane >> 4) + r; jD[r] = lane & 15; }
            else if (dF == 1) { iD[r] = (lane >> 4) + 4 * r; jD[r] = lane & 15; }
            else if (dF == 2) { jD[r] = 4 * (lane >> 4) + r; iD[r] = lane & 15; }
            else              { jD[r] = (lane >> 4) + 4 * r; iD[r] = lane & 15; }
        }

        float* Asw = (float*)(smem + (size_t)w * 10240);   // 16 x 80 f32
        float* Bsw = Asw + 1280;

        d4 acc[4][4];
#pragma unroll
        for (int f = 0; f < 4; ++f)
#pragma unroll
            for (int g = 0; g < 4; ++g) acc[f][g] = (d4)0.0;

        float4 sa[4], sb[4];
#pragma unroll
        for (int j = 0; j < 4; ++j) {             // load tile 0
            sa[j] = *(const float4*)(Ag + kw + 4 * j);
            sb[j] = *(const float4*)(Bg + kw + 4 * j);
        }
        for (int k0 = kw; k0 < N_DIM; k0 += 2 * BK) {
#pragma unroll
            for (int j = 0; j < 4; ++j) {         // stage [k][row]
                Asw[(4 * j + 0) * STRD + lane] = sa[j].x;
                Asw[(4 * j + 1) * STRD + lane] = sa[j].y;
                Asw[(4 * j + 2) * STRD + lane] = sa[j].z;
                Asw[(4 * j + 3) * STRD + lane] = sa[j].w;
                Bsw[(4 * j + 0) * STRD + lane] = sb[j].x;
                Bsw[(4 * j + 1) * STRD + lane] = sb[j].y;
                Bsw[(4 * j + 2) * STRD + lane] = sb[j].z;
                Bsw[(4 * j + 3) * STRD + lane] = sb[j].w;
            }
            if (k0 + 2 * BK < N_DIM) {            // prefetch next tile
#pragma unroll
                for (int j = 0; j < 4; ++j) {
                    sa[j] = *(const float4*)(Ag + k0 + 2 * BK + 4 * j);
                    sb[j] = *(const float4*)(Bg + k0 + 2 * BK + 4 * j);
                }
            }
#pragma unroll
            for (int jq = 0; jq < 4; ++jq) {      // 4 k-quads, ascending
                double av[4], bv[4];
#pragma unroll
                for (int f = 0; f < 4; ++f)
                    av[f] = (double)Asw[(4 * jq + kA) * STRD + 16 * f + mA];
#pragma unroll
                for (int g = 0; g < 4; ++g)
                    bv[g] = (double)Bsw[(4 * jq + kB) * STRD + 16 * g + nB];
#pragma unroll
                for (int f = 0; f < 4; ++f)
#pragma unroll
                    for (int g = 0; g < 4; ++g)
                        acc[f][g] = __builtin_amdgcn_mfma_f64_16x16x4f64(
                            av[f], bv[g], acc[f][g], 0, 0, 0);
            }
        }

        __syncthreads();
        double* cbuf = (double*)smem;             // 4096 doubles = 32KB
        if (w == 1) {
#pragma unroll
            for (int f = 0; f < 4; ++f)
#pragma unroll
                for (int g = 0; g < 4; ++g)
#pragma unroll
                    for (int r = 0; r < 4; ++r)
                        cbuf[((f * 4 + g) * 4 + r) * 64 + lane] = acc[f][g][r];
        }
        __syncthreads();
        if (w == 0) {
#pragma unroll
            for (int f = 0; f < 4; ++f)
#pragma unroll
                for (int g = 0; g < 4; ++g)
#pragma unroll
                    for (int r = 0; r < 4; ++r)
                        acc[f][g][r] += cbuf[((f * 4 + g) * 4 + r) * 64 + lane];
#pragma unroll
            for (int f = 0; f < 4; ++f)
#pragma unroll
                for (int r = 0; r < 4; ++r) {
                    int row = row0 + 16 * f + iD[r];
                    double* Crow = C + (size_t)row * N_DIM + col0 + jD[r];
#pragma unroll
                    for (int g = 0; g < 4; ++g)
                        Crow[16 * g] = acc[f][g][r];
                }
        }
    } else {
        // ================= vector fallback (v4, proven) =================
        const int tx = lane & 7;                  // col 4-group
        const int ty = lane >> 3;                 // row 4-group
        float* Asw = (float*)smem + (size_t)w * 2176;
        float* Bsw = Asw + 1088;

        double acc[8][8];
#pragma unroll
        for (int i = 0; i < 8; ++i)
#pragma unroll
            for (int j = 0; j < 8; ++j) acc[i][j] = 0.0;

        float4 sa[4], sb[4];
#pragma unroll
        for (int j = 0; j < 4; ++j) {
            sa[j] = *(const float4*)(Ag + kw + 4 * j);
            sb[j] = *(const float4*)(Bg + kw + 4 * j);
        }
        for (int k0 = kw; k0 < N_DIM; k0 += 2 * BK) {
#pragma unroll
            for (int j = 0; j < 4; ++j) {
                Asw[(4 * j + 0) * LDSS + lane] = sa[j].x;
                Asw[(4 * j + 1) * LDSS + lane] = sa[j].y;
                Asw[(4 * j + 2) * LDSS + lane] = sa[j].z;
                Asw[(4 * j + 3) * LDSS + lane] = sa[j].w;
                Bsw[(4 * j + 0) * LDSS + lane] = sb[j].x;
                Bsw[(4 * j + 1) * LDSS + lane] = sb[j].y;
                Bsw[(4 * j + 2) * LDSS + lane] = sb[j].z;
                Bsw[(4 * j + 3) * LDSS + lane] = sb[j].w;
            }
            if (k0 + 2 * BK < N_DIM) {
#pragma unroll
                for (int j = 0; j < 4; ++j) {
                    sa[j] = *(const float4*)(Ag + k0 + 2 * BK + 4 * j);
                    sb[j] = *(const float4*)(Bg + k0 + 2 * BK + 4 * j);
                }
            }
#pragma unroll
            for (int k = 0; k < BK; ++k) {
                float4 alo = *(const float4*)&Asw[k * LDSS + 4 * ty];
                float4 ahi = *(const float4*)&Asw[k * LDSS + 32 + 4 * ty];
                float4 blo = *(const float4*)&Bsw[k * LDSS + 4 * tx];
                float4 bhi = *(const float4*)&Bsw[k * LDSS + 32 + 4 * tx];
                double a[8], b[8];
                a[0] = (double)alo.x; a[1] = (double)alo.y;
                a[2] = (double)alo.z; a[3] = (double)alo.w;
                a[4] = (double)ahi.x; a[5] = (double)ahi.y;
                a[6] = (double)ahi.z; a[7] = (double)ahi.w;
                b[0] = (double)blo.x; b[1] = (double)blo.y;
                b[2] = (double)blo.z; b[3] = (double)blo.w;
                b[4] = (double)bhi.x; b[5] = (double)bhi.y;
                b[6] = (double)bhi.z; b[7] = (double)bhi.w;
#pragma unroll
                for (int i = 0; i < 8; ++i)
#pragma unroll
                    for (int j = 0; j < 8; ++j)
                        acc[i][j] = fma(a[i], b[j], acc[i][j]);
            }
        }

        __syncthreads();
        double* cbuf = (double*)smem;
        if (w == 1) {
#pragma unroll
            for (int e = 0; e < 64; ++e)
                cbuf[e * 64 + lane] = acc[e >> 3][e & 7];
        }
        __syncthreads();
        if (w == 0) {
#pragma unroll
            for (int i = 0; i < 8; ++i)
#pragma unroll
                for (int j = 0; j < 8; ++j)
                    acc[i][j] += cbuf[(i * 8 + j) * 64 + lane];
#pragma unroll
            for (int i = 0; i < 8; ++i) {
                int r = row0 + ((i < 4) ? (4 * ty + i) : (32 + 4 * ty + i - 4));
                double* Crow = C + (size_t)r * N_DIM + col0;
#pragma unroll
                for (int jg = 0; jg < 2; ++jg) {
                    int cbase = (jg == 0) ? (4 * tx) : (32 + 4 * tx);
                    d2 v0, v1;
                    v0.x = acc[i][4 * jg + 0]; v0.y = acc[i][4 * jg + 1];
                    v1.x = acc[i][4 * jg + 2]; v1.y = acc[i][4 * jg + 3];
                    *(d2*)(Crow + cbase)     = v0;
                    *(d2*)(Crow + cbase + 2) = v1;
                }
            }
        }
    }
}

// ---- BN column stats, two-stage deterministic (layout-agnostic) -----------
__global__ __launch_bounds__(256)
void col_stats_partial(const double* __restrict__ h, double* __restrict__ psum,
                       double* __restrict__ psum2) {
    int m = blockIdx.x * 256 + threadIdx.x;       // 8 col blocks
    int chunk = blockIdx.y;                        // 16 row chunks of 128
    double s = 0.0, s2 = 0.0;
    int r0 = chunk * 128;
    for (int r = r0; r < r0 + 128; ++r) {
        double v = h[(size_t)r * N_DIM + m];
        s += v;
        s2 = fma(v, v, s2);
    }
    psum[chunk * N_DIM + m] = s;
    psum2[chunk * N_DIM + m] = s2;
}

__global__ __launch_bounds__(256)
void col_stats_final(const double* __restrict__ psum, const double* __restrict__ psum2,
                     const float* __restrict__ gamma, const float* __restrict__ beta,
                     double* __restrict__ scale, double* __restrict__ shift) {
    int m = blockIdx.x * 256 + threadIdx.x;
    double s = 0.0, s2 = 0.0;
    for (int c = 0; c < 16; ++c) { s += psum[c * N_DIM + m]; s2 += psum2[c * N_DIM + m]; }
    double mean = s * (1.0 / 2048.0);
    double var = s2 * (1.0 / 2048.0) - mean * mean;
    double istd = 1.0 / sqrt(var + 1e-5);
    double sc = istd * (double)gamma[m];
    scale[m] = sc;
    shift[m] = (double)beta[m] - mean * sc;
}

// ---- fused BN-apply + triple LIF + output ---------------------------------
__global__ __launch_bounds__(256)
void fused_lif_kernel(const float* __restrict__ x, const double* __restrict__ h,
                      const double* __restrict__ scale, const double* __restrict__ shift,
                      const double* __restrict__ ssum, const double* __restrict__ tsum,
                      float* __restrict__ out) {
    int idx = blockIdx.x * 256 + threadIdx.x;     // b*N + n
    int n = idx & (N_DIM - 1);
    int b = idx >> 11;
    double sc = scale[n], sh = shift[n];
    double ts = tsum[idx];
    double v1 = 0.0, v2 = 0.0, v3 = 0.0;
    for (int t = 0; t < T_DIM; ++t) {
        size_t off = (size_t)(t * B_DIM + b) * N_DIM + n;
        double hv = fma(h[off], sc, sh);
        v1 = v1 * 0.5 + hv;
        bool s1 = (v1 >= 1.0); if (s1) v1 = 0.0;
        double in2 = s1 ? ssum[t * B_DIM + b] : 0.0;
        v2 = v2 * 0.5 + in2;
        bool s2 = (v2 >= 1.0); if (s2) v2 = 0.0;
        double in3 = s1 ? ts : 0.0;
        v3 = v3 * 0.5 + in3;
        bool s3 = (v3 >= 1.0); if (s3) v3 = 0.0;
        out[off] = x[off] + ((s2 && s3) ? 1.0f : 0.0f);
    }
}

extern "C" void kernel_launch(void* const* d_in, const int* in_sizes, int n_in,
                              void* d_out, int out_size, void* d_ws, size_t ws_size,
                              hipStream_t stream) {
    const float* x     = (const float*)d_in[0];   // [16,128,2048]
    const float* W     = (const float*)d_in[1];   // [2048,2048]
    const float* gamma = (const float*)d_in[2];   // [2048]
    const float* beta  = (const float*)d_in[3];   // [2048]
    float* out = (float*)d_out;

    char* ws = (char*)d_ws;
    double* h     = (double*)(ws + WS_H);
    double* tsum  = (double*)(ws + WS_TSUM);
    double* psum  = (double*)(ws + WS_PSUM);
    double* psum2 = (double*)(ws + WS_PSUM2);
    double* ssum  = (double*)(ws + WS_SSUM);
    double* scale = (double*)(ws + WS_SCALE);
    double* shift = (double*)(ws + WS_SHIFT);
    unsigned int* flag = (unsigned int*)(ws + WS_FLAG);

    mfma_probe_kernel<<<1, 64, 0, stream>>>(flag);
    spatial_sum_kernel<<<TB, 256, 0, stream>>>(x, ssum);
    temporal_sum_kernel<<<(B_DIM * N_DIM) / 256, 256, 0, stream>>>(x, tsum);
    gemm_hybrid<<<dim3(N_DIM / 64, TB / 64), 128, 0, stream>>>(x, W, h, flag);
    col_stats_partial<<<dim3(8, 16), 256, 0, stream>>>(h, psum, psum2);
    col_stats_final<<<8, 256, 0, stream>>>(psum, psum2, gamma, beta, scale, shift);
    fused_lif_kernel<<<(B_DIM * N_DIM) / 256, 256, 0, stream>>>(x, h, scale, shift, ssum, tsum, out);
}

// Round 11
// 366.853 us; speedup vs baseline: 1.4169x; 1.0165x over previous
//
#include <hip/hip_runtime.h>
#include <math.h>

// Problem constants
#define T_DIM 16
#define B_DIM 128
#define N_DIM 2048
#define TB    (T_DIM * B_DIM)   // 2048 rows of the GEMM

// Workspace layout (bytes). Total ~36.75 MB.
#define WS_H      0
#define WS_TSUM   33554432
#define WS_PSUM   35651584      // [32][2048] f64 per-rowband col sums
#define WS_PSUM2  36175872      // [32][2048] f64 per-rowband col sq-sums
#define WS_SSUM   36700160
#define WS_SCALE  36716544
#define WS_SHIFT  36732928
#define WS_FLAG   36749312

typedef __attribute__((ext_vector_type(2))) double d2;
typedef __attribute__((ext_vector_type(4))) double d4;

// ---- MFMA f64 wiring probe -------------------------------------------------
__device__ __forceinline__ double probeA(int m, int k) {
    return (double)((m * 7 + k * 13) % 23 - 11);
}
__device__ __forceinline__ double probeB(int k, int n) {
    return (double)((k * 5 + n * 3) % 19 - 9);
}

// Hypothesis encoding fh = ab*4 + dF;  ab = aF + 2*bF.
//  A-form 0: m=l&15,k=l>>4   1: m=l>>2,k=l&3
//  B-form 0: n=l&15,k=l>>4   1: n=l>>2,k=l&3
//  D-form 0: i=4*(l>>4)+r,j=l&15   1: i=(l>>4)+4r,j=l&15
//         2: j=4*(l>>4)+r,i=l&15   3: j=(l>>4)+4r,i=l&15
__global__ void mfma_probe_kernel(unsigned int* flag) {
    int l = threadIdx.x;                 // one wave
    __shared__ double Cref[16][16];
    int i0 = l >> 2, j0 = (l & 3) << 2;
    for (int jj = 0; jj < 4; ++jj) {
        double s = 0.0;
        for (int k = 0; k < 4; ++k) s += probeA(i0, k) * probeB(k, j0 + jj);
        Cref[i0][j0 + jj] = s;
    }
    __syncthreads();
    unsigned int win = 0xFFFFFFFFu;
    for (int ab = 0; ab < 4; ++ab) {
        int aF = ab & 1, bF = (ab >> 1) & 1;
        int mA = aF ? (l >> 2) : (l & 15);
        int kA = aF ? (l & 3)  : (l >> 4);
        int nB = bF ? (l >> 2) : (l & 15);
        int kB = bF ? (l & 3)  : (l >> 4);
        d4 d = (d4)0.0;
        d = __builtin_amdgcn_mfma_f64_16x16x4f64(probeA(mA, kA), probeB(kB, nB), d, 0, 0, 0);
        for (int dF = 0; dF < 4; ++dF) {
            double err = 0.0;
            for (int r = 0; r < 4; ++r) {
                int ii, jj;
                if (dF == 0)      { ii = 4 * (l >> 4) + r; jj = l & 15; }
                else if (dF == 1) { ii = (l >> 4) + 4 * r; jj = l & 15; }
                else if (dF == 2) { jj = 4 * (l >> 4) + r; ii = l & 15; }
                else              { jj = (l >> 4) + 4 * r; ii = l & 15; }
                err = fmax(err, fabs(d[r] - Cref[ii][jj]));
            }
            for (int off = 1; off < 64; off <<= 1)
                err = fmax(err, __shfl_xor(err, off, 64));
            if (err < 1e-9 && win == 0xFFFFFFFFu)
                win = (unsigned)(ab * 4 + dF);
        }
    }
    if (l == 0) flag[0] = win;
}

// ---- spatial sum over last dim: one block per (t,b) row -------------------
__global__ __launch_bounds__(256)
void spatial_sum_kernel(const float* __restrict__ x, double* __restrict__ ssum) {
    int row = blockIdx.x;
    int tid = threadIdx.x;
    const float* xr = x + (size_t)row * N_DIM;
    double s = 0.0;
    for (int i = tid; i < N_DIM; i += 256) s += (double)xr[i];
    for (int off = 32; off > 0; off >>= 1) s += __shfl_down(s, off, 64);
    __shared__ double wsum[4];
    int lane = tid & 63, wv = tid >> 6;
    if (lane == 0) wsum[wv] = s;
    __syncthreads();
    if (tid == 0) ssum[row] = (wsum[0] + wsum[1]) + (wsum[2] + wsum[3]);
}

// ---- temporal sum over t: one thread per (b,n) ----------------------------
__global__ __launch_bounds__(256)
void temporal_sum_kernel(const float* __restrict__ x, double* __restrict__ tsum) {
    int idx = blockIdx.x * 256 + threadIdx.x;
    double s = 0.0;
    for (int t = 0; t < T_DIM; ++t)
        s += (double)x[(size_t)t * (B_DIM * N_DIM) + idx];
    tsum[idx] = s;
}

// ---- GEMM h[row,m] = sum_n x[row,n] * W[m,n] ------------------------------
// v10: 64x64 tile, TWO waves/block, in-block split-K, probe-adaptive f64
// MFMA (R10: 291us, MfmaUtil 80%). NEW: (1) statically-addressed x2-unrolled
// per-wave DOUBLE-BUFFERED staging -- write->read distance = one compute
// phase, no dynamic buffer indexing; (2) fused per-column BN partials via a
// layout-agnostic 64x64 LDS scatter (runtime iD/jD) + column reduction in
// wave0 (same-wave DS ordering -> no extra barrier).
#define BK 16
#define LDSS 68   // vector path stride
#define STRD 80   // mfma path stride (2-way aliasing = free)

#define MFMA_LOAD(koff)                                             \
    _Pragma("unroll")                                               \
    for (int j = 0; j < 4; ++j) {                                   \
        sa[j] = *(const float4*)(Ag + (koff) + 4 * j);              \
        sb[j] = *(const float4*)(Bg + (koff) + 4 * j);              \
    }

#define MFMA_STAGE(Ab, Bb)                                          \
    _Pragma("unroll")                                               \
    for (int j = 0; j < 4; ++j) {                                   \
        (Ab)[(4 * j + 0) * STRD + lane] = sa[j].x;                  \
        (Ab)[(4 * j + 1) * STRD + lane] = sa[j].y;                  \
        (Ab)[(4 * j + 2) * STRD + lane] = sa[j].z;                  \
        (Ab)[(4 * j + 3) * STRD + lane] = sa[j].w;                  \
        (Bb)[(4 * j + 0) * STRD + lane] = sb[j].x;                  \
        (Bb)[(4 * j + 1) * STRD + lane] = sb[j].y;                  \
        (Bb)[(4 * j + 2) * STRD + lane] = sb[j].z;                  \
        (Bb)[(4 * j + 3) * STRD + lane] = sb[j].w;                  \
    }

#define MFMA_COMPUTE(Ab, Bb)                                        \
    _Pragma("unroll")                                               \
    for (int jq = 0; jq < 4; ++jq) {                                \
        double av[4], bv[4];                                        \
        _Pragma("unroll")                                           \
        for (int f = 0; f < 4; ++f)                                 \
            av[f] = (double)(Ab)[(4 * jq + kA) * STRD + 16 * f + mA]; \
        _Pragma("unroll")                                           \
        for (int g = 0; g < 4; ++g)                                 \
            bv[g] = (double)(Bb)[(4 * jq + kB) * STRD + 16 * g + nB]; \
        _Pragma("unroll")                                           \
        for (int f = 0; f < 4; ++f)                                 \
            _Pragma("unroll")                                       \
            for (int g = 0; g < 4; ++g)                             \
                acc[f][g] = __builtin_amdgcn_mfma_f64_16x16x4f64(   \
                    av[f], bv[g], acc[f][g], 0, 0, 0);              \
    }

__global__ __launch_bounds__(128, 2)
void gemm_hybrid(const float* __restrict__ A, const float* __restrict__ Bw,
                 double* __restrict__ C, double* __restrict__ psum,
                 double* __restrict__ psum2, const unsigned int* __restrict__ flag) {
    __shared__ __align__(16) char smem[40960];   // 2 waves x 2 bufs x 10240B; cbuf 32KB
    const int t    = threadIdx.x;
    const int lane = t & 63;
    const int w    = t >> 6;
    const int row0 = blockIdx.y * 64;
    const int col0 = blockIdx.x * 64;
    const int band = blockIdx.y;
    const unsigned int fh = flag[0];

    const float* Ag = A  + (size_t)(row0 + lane) * N_DIM;
    const float* Bg = Bw + (size_t)(col0 + lane) * N_DIM;
    const int kw = w * BK;
    double* cbuf = (double*)smem;                // 4096 doubles = 32KB

    if (fh <= 15u) {
        // ================= MFMA path =================
        const int dF = fh & 3, ab = fh >> 2;
        const int aF = ab & 1, bF = (ab >> 1) & 1;
        const int mA = aF ? (lane >> 2) : (lane & 15);
        const int kA = aF ? (lane & 3)  : (lane >> 4);
        const int nB = bF ? (lane >> 2) : (lane & 15);
        const int kB = bF ? (lane & 3)  : (lane >> 4);
        int iD[4], jD[4];
#pragma unroll
        for (int r = 0; r < 4; ++r) {
            if (dF == 0)      { iD[r] = 4 * (lane >> 4) + r; jD[r] = lane & 15; }
            else if (dF == 1) { iD[r] = (lane >> 4) + 4 * r; jD[r] = lane & 15; }
            else if (dF == 2) { jD[r] = 4 * (lane >> 4) + r; iD[r] = lane & 15; }
            else              { jD[r] = (lane >> 4) + 4 * r; iD[r] = lane & 15; }
        }

        float* A0 = (float*)(smem + (size_t)w * 20480);
        float* B0 = A0 + 1280;
        float* A1 = A0 + 2560;
        float* B1 = A0 + 3840;

        d4 acc[4][4];
#pragma unroll
        for (int f = 0; f < 4; ++f)
#pragma unroll
            for (int g = 0; g < 4; ++g) acc[f][g] = (d4)0.0;

        float4 sa[4], sb[4];
        MFMA_LOAD(kw)                 // tile 0
        MFMA_STAGE(A0, B0)            // -> buf0
        MFMA_LOAD(kw + 32)            // tile 1

        for (int k0 = kw; k0 < N_DIM; k0 += 64) {
            MFMA_STAGE(A1, B1)        // tile k0+32 -> buf1
            if (k0 + 64 < N_DIM) { MFMA_LOAD(k0 + 64) }
            MFMA_COMPUTE(A0, B0)      // tile k0
            if (k0 + 64 < N_DIM) {
                MFMA_STAGE(A0, B0)    // tile k0+64 -> buf0
                if (k0 + 96 < N_DIM) { MFMA_LOAD(k0 + 96) }
            }
            MFMA_COMPUTE(A1, B1)      // tile k0+32
        }

        __syncthreads();
        if (w == 1) {
#pragma unroll
            for (int f = 0; f < 4; ++f)
#pragma unroll
                for (int g = 0; g < 4; ++g)
#pragma unroll
                    for (int r = 0; r < 4; ++r)
                        cbuf[((f * 4 + g) * 4 + r) * 64 + lane] = acc[f][g][r];
        }
        __syncthreads();
        if (w == 0) {
#pragma unroll
            for (int f = 0; f < 4; ++f)
#pragma unroll
                for (int g = 0; g < 4; ++g)
#pragma unroll
                    for (int r = 0; r < 4; ++r)
                        acc[f][g][r] += cbuf[((f * 4 + g) * 4 + r) * 64 + lane];
            // store C
#pragma unroll
            for (int f = 0; f < 4; ++f)
#pragma unroll
                for (int r = 0; r < 4; ++r) {
                    int row = row0 + 16 * f + iD[r];
                    double* Crow = C + (size_t)row * N_DIM + col0 + jD[r];
#pragma unroll
                    for (int g = 0; g < 4; ++g)
                        Crow[16 * g] = acc[f][g][r];
                }
            // layout-agnostic BN partials: scatter acc -> cbuf[row][col],
            // then column-sum (same-wave DS ordering -> no barrier needed)
#pragma unroll
            for (int f = 0; f < 4; ++f)
#pragma unroll
                for (int r = 0; r < 4; ++r)
#pragma unroll
                    for (int g = 0; g < 4; ++g)
                        cbuf[(16 * f + iD[r]) * 64 + 16 * g + jD[r]] = acc[f][g][r];
            double s = 0.0, q = 0.0;
#pragma unroll
            for (int r = 0; r < 64; ++r) {
                double v = cbuf[r * 64 + lane];
                s += v;
                q = fma(v, v, q);
            }
            psum [band * N_DIM + col0 + lane] = s;
            psum2[band * N_DIM + col0 + lane] = q;
        }
    } else {
        // ================= vector fallback (v4, proven) =================
        const int tx = lane & 7;
        const int ty = lane >> 3;
        float* Asw = (float*)smem + (size_t)w * 2176;
        float* Bsw = Asw + 1088;

        double acc[8][8];
#pragma unroll
        for (int i = 0; i < 8; ++i)
#pragma unroll
            for (int j = 0; j < 8; ++j) acc[i][j] = 0.0;

        float4 sa[4], sb[4];
#pragma unroll
        for (int j = 0; j < 4; ++j) {
            sa[j] = *(const float4*)(Ag + kw + 4 * j);
            sb[j] = *(const float4*)(Bg + kw + 4 * j);
        }
        for (int k0 = kw; k0 < N_DIM; k0 += 2 * BK) {
#pragma unroll
            for (int j = 0; j < 4; ++j) {
                Asw[(4 * j + 0) * LDSS + lane] = sa[j].x;
                Asw[(4 * j + 1) * LDSS + lane] = sa[j].y;
                Asw[(4 * j + 2) * LDSS + lane] = sa[j].z;
                Asw[(4 * j + 3) * LDSS + lane] = sa[j].w;
                Bsw[(4 * j + 0) * LDSS + lane] = sb[j].x;
                Bsw[(4 * j + 1) * LDSS + lane] = sb[j].y;
                Bsw[(4 * j + 2) * LDSS + lane] = sb[j].z;
                Bsw[(4 * j + 3) * LDSS + lane] = sb[j].w;
            }
            if (k0 + 2 * BK < N_DIM) {
#pragma unroll
                for (int j = 0; j < 4; ++j) {
                    sa[j] = *(const float4*)(Ag + k0 + 2 * BK + 4 * j);
                    sb[j] = *(const float4*)(Bg + k0 + 2 * BK + 4 * j);
                }
            }
#pragma unroll
            for (int k = 0; k < BK; ++k) {
                float4 alo = *(const float4*)&Asw[k * LDSS + 4 * ty];
                float4 ahi = *(const float4*)&Asw[k * LDSS + 32 + 4 * ty];
                float4 blo = *(const float4*)&Bsw[k * LDSS + 4 * tx];
                float4 bhi = *(const float4*)&Bsw[k * LDSS + 32 + 4 * tx];
                double a[8], b[8];
                a[0] = (double)alo.x; a[1] = (double)alo.y;
                a[2] = (double)alo.z; a[3] = (double)alo.w;
                a[4] = (double)ahi.x; a[5] = (double)ahi.y;
                a[6] = (double)ahi.z; a[7] = (double)ahi.w;
                b[0] = (double)blo.x; b[1] = (double)blo.y;
                b[2] = (double)blo.z; b[3] = (double)blo.w;
                b[4] = (double)bhi.x; b[5] = (double)bhi.y;
                b[6] = (double)bhi.z; b[7] = (double)bhi.w;
#pragma unroll
                for (int i = 0; i < 8; ++i)
#pragma unroll
                    for (int j = 0; j < 8; ++j)
                        acc[i][j] = fma(a[i], b[j], acc[i][j]);
            }
        }

        __syncthreads();
        if (w == 1) {
#pragma unroll
            for (int e = 0; e < 64; ++e)
                cbuf[e * 64 + lane] = acc[e >> 3][e & 7];
        }
        __syncthreads();
        if (w == 0) {
#pragma unroll
            for (int i = 0; i < 8; ++i)
#pragma unroll
                for (int j = 0; j < 8; ++j)
                    acc[i][j] += cbuf[(i * 8 + j) * 64 + lane];
#pragma unroll
            for (int i = 0; i < 8; ++i) {
                int r = row0 + ((i < 4) ? (4 * ty + i) : (32 + 4 * ty + i - 4));
                double* Crow = C + (size_t)r * N_DIM + col0;
#pragma unroll
                for (int jg = 0; jg < 2; ++jg) {
                    int cbase = (jg == 0) ? (4 * tx) : (32 + 4 * tx);
                    d2 v0, v1;
                    v0.x = acc[i][4 * jg + 0]; v0.y = acc[i][4 * jg + 1];
                    v1.x = acc[i][4 * jg + 2]; v1.y = acc[i][4 * jg + 3];
                    *(d2*)(Crow + cbase)     = v0;
                    *(d2*)(Crow + cbase + 2) = v1;
                }
            }
            // BN partials via cbuf scatter + column reduction
#pragma unroll
            for (int i = 0; i < 8; ++i) {
                int rr = (i < 4) ? (4 * ty + i) : (32 + 4 * ty + i - 4);
#pragma unroll
                for (int j = 0; j < 8; ++j) {
                    int cc = (j < 4) ? (4 * tx + j) : (32 + 4 * tx + j - 4);
                    cbuf[rr * 64 + cc] = acc[i][j];
                }
            }
            double s = 0.0, q = 0.0;
#pragma unroll
            for (int r = 0; r < 64; ++r) {
                double v = cbuf[r * 64 + lane];
                s += v;
                q = fma(v, v, q);
            }
            psum [band * N_DIM + col0 + lane] = s;
            psum2[band * N_DIM + col0 + lane] = q;
        }
    }
}

// ---- BN final: reduce 32 rowband partials, build scale/shift --------------
__global__ __launch_bounds__(256)
void col_stats_final(const double* __restrict__ psum, const double* __restrict__ psum2,
                     const float* __restrict__ gamma, const float* __restrict__ beta,
                     double* __restrict__ scale, double* __restrict__ shift) {
    int m = blockIdx.x * 256 + threadIdx.x;
    double s = 0.0, s2 = 0.0;
    for (int c = 0; c < 32; ++c) { s += psum[c * N_DIM + m]; s2 += psum2[c * N_DIM + m]; }
    double mean = s * (1.0 / 2048.0);
    double var = s2 * (1.0 / 2048.0) - mean * mean;
    double istd = 1.0 / sqrt(var + 1e-5);
    double sc = istd * (double)gamma[m];
    scale[m] = sc;
    shift[m] = (double)beta[m] - mean * sc;
}

// ---- fused BN-apply + triple LIF + output ---------------------------------
__global__ __launch_bounds__(256)
void fused_lif_kernel(const float* __restrict__ x, const double* __restrict__ h,
                      const double* __restrict__ scale, const double* __restrict__ shift,
                      const double* __restrict__ ssum, const double* __restrict__ tsum,
                      float* __restrict__ out) {
    int idx = blockIdx.x * 256 + threadIdx.x;
    int n = idx & (N_DIM - 1);
    int b = idx >> 11;
    double sc = scale[n], sh = shift[n];
    double ts = tsum[idx];
    double v1 = 0.0, v2 = 0.0, v3 = 0.0;
    for (int t = 0; t < T_DIM; ++t) {
        size_t off = (size_t)(t * B_DIM + b) * N_DIM + n;
        double hv = fma(h[off], sc, sh);
        v1 = v1 * 0.5 + hv;
        bool s1 = (v1 >= 1.0); if (s1) v1 = 0.0;
        double in2 = s1 ? ssum[t * B_DIM + b] : 0.0;
        v2 = v2 * 0.5 + in2;
        bool s2 = (v2 >= 1.0); if (s2) v2 = 0.0;
        double in3 = s1 ? ts : 0.0;
        v3 = v3 * 0.5 + in3;
        bool s3 = (v3 >= 1.0); if (s3) v3 = 0.0;
        out[off] = x[off] + ((s2 && s3) ? 1.0f : 0.0f);
    }
}

extern "C" void kernel_launch(void* const* d_in, const int* in_sizes, int n_in,
                              void* d_out, int out_size, void* d_ws, size_t ws_size,
                              hipStream_t stream) {
    const float* x     = (const float*)d_in[0];   // [16,128,2048]
    const float* W     = (const float*)d_in[1];   // [2048,2048]
    const float* gamma = (const float*)d_in[2];   // [2048]
    const float* beta  = (const float*)d_in[3];   // [2048]
    float* out = (float*)d_out;

    char* ws = (char*)d_ws;
    double* h     = (double*)(ws + WS_H);
    double* tsum  = (double*)(ws + WS_TSUM);
    double* psum  = (double*)(ws + WS_PSUM);
    double* psum2 = (double*)(ws + WS_PSUM2);
    double* ssum  = (double*)(ws + WS_SSUM);
    double* scale = (double*)(ws + WS_SCALE);
    double* shift = (double*)(ws + WS_SHIFT);
    unsigned int* flag = (unsigned int*)(ws + WS_FLAG);

    mfma_probe_kernel<<<1, 64, 0, stream>>>(flag);
    spatial_sum_kernel<<<TB, 256, 0, stream>>>(x, ssum);
    temporal_sum_kernel<<<(B_DIM * N_DIM) / 256, 256, 0, stream>>>(x, tsum);
    gemm_hybrid<<<dim3(N_DIM / 64, TB / 64), 128, 0, stream>>>(x, W, h, psum, psum2, flag);
    col_stats_final<<<8, 256, 0, stream>>>(psum, psum2, gamma, beta, scale, shift);
    fused_lif_kernel<<<(B_DIM * N_DIM) / 256, 256, 0, stream>>>(x, h, scale, shift, ssum, tsum, out);
}